// Round 14
// baseline (665.949 us; speedup 1.0000x reference)
//
#include <hip/hip_runtime.h>
#include <hip/hip_bf16.h>
#include <math.h>

#define TT 1024
#define KK 128
#define BB 512
#define NBLK 32
#define TPB 192
#define NS 8
#define LN2F 0.69314718056f

typedef float  f32x4  __attribute__((ext_vector_type(4)));
typedef short  bf16x8 __attribute__((ext_vector_type(8)));

__device__ __forceinline__ unsigned cvt_pk_bf16(float lo, float hi) {
    unsigned r;
    asm("v_cvt_pk_bf16_f32 %0, %1, %2" : "=v"(r) : "v"(lo), "v"(hi));
    return r;
}
__device__ __forceinline__ unsigned short bf16_rtn(float f) {
    union { float f; unsigned u; } v; v.f = f;
    return (unsigned short)((v.u + 0x7FFFu + ((v.u >> 16) & 1u)) >> 16);
}
#define LGKM0() asm volatile("s_waitcnt lgkmcnt(0)" ::: "memory")

// Producer/consumer CRF forward, R14: reg-double-buffered C + lane-linear LDS.
// Ring slot layout: float offset = tt*256 + kg*64 + col*4 + e  -> every LDS
// access (producer write, consumer read) is addr16B = const + lane:
// contiguous, conflict-free.
// Consumer serial chain per step: B-pack -> 32 MFMA (kt-major) -> D-update.
// C_{t+1} is read into regs DURING step t's MFMA train (flag prefetched one
// step earlier); slot freed right after reg-capture. ready-flag atomicAdd is
// lane-predicated (+1/wave; all-lane atomicAdd gets wave-coalesced to +64
// and never gates -- R13 latent race, fixed).
__global__ __launch_bounds__(TPB, 1)
void crf_fwd_kernel(const float* __restrict__ feats,
                    const float* __restrict__ trans,
                    float* __restrict__ out)
{
    const int tid  = threadIdx.x;
    const int wv   = tid >> 6;
    const int lane = tid & 63;

    __shared__ __align__(16) float ring[NS][2048];   // 64 KB
    __shared__ int ready[NS];
    __shared__ int consr;    // count of C_t captured into consumer regs

    if (tid < NS) ready[tid] = 0;
    if (tid == 0) consr = 0;
    __syncthreads();         // only full-block barrier

    if (wv < 2) {
        // ================= PRODUCER (waves 0,1; wave handles tt = wv*4..wv*4+3)
        const int c = lane & 15;          // seq
        const int k = lane >> 4;          // kg quad
        const float* fb = feats + (size_t)(blockIdx.x*16 + c)*TT*KK + wv*64 + k*4;
        volatile int* cp = &consr;

        f32x4 F[4][4];                    // 4-step lookahead, 4 tt-tiles each
        #pragma unroll
        for (int j = 0; j < 4; ++j)
            #pragma unroll
            for (int i = 0; i < 4; ++i)
                F[j][i] = *(const f32x4*)(fb + (size_t)j*KK + i*16);

        for (int t = 0; t < TT; t += 4) {
            #pragma unroll
            for (int j = 0; j < 4; ++j) {
                const int tc = t + j;
                while (*cp < tc - 7) {}           // room: slot holds C_{tc-8}
                const int s = tc & (NS - 1);
                float* dst = &ring[s][wv*1024 + k*64 + c*4];
                #pragma unroll
                for (int i = 0; i < 4; ++i) {
                    f32x4 e;
                    e.x = __expf(F[j][i].x); e.y = __expf(F[j][i].y);
                    e.z = __expf(F[j][i].z); e.w = __expf(F[j][i].w);
                    *(f32x4*)(dst + i*256) = e;   // addr16 = const + lane
                }
                LGKM0();                          // data visible before flag
                if (lane == 0) atomicAdd(&ready[s], 1);
                if (tc + 4 < TT) {
                    #pragma unroll
                    for (int i = 0; i < 4; ++i)
                        F[j][i] = *(const f32x4*)(fb + (size_t)(tc+4)*KK + i*16);
                }
            }
        }
        return;
    }

    // ================= CONSUMER (wave 2) =================
    const int col = lane & 15;
    const int kg  = lane >> 4;
    const int seq = blockIdx.x * 16 + col;

    // A fragments (R11/R12/R13-verified wiring):
    // tag a <-> (tt=a>>4, rr=a&15); kpos(a)=(tt>>1)*32+(rr>>2)*8+(tt&1)*4+(rr&3)
    union AB { bf16x8 v; unsigned u[4]; };
    AB A[8][4];
    #pragma unroll
    for (int tt = 0; tt < 8; ++tt)
        #pragma unroll
        for (int kt = 0; kt < 4; ++kt) {
            unsigned short h[8];
            #pragma unroll
            for (int j = 0; j < 8; ++j) {
                const int frm = (2*kt + (j >> 2))*16 + kg*4 + (j & 3);
                const int to  = tt*16 + col;
                h[j] = bf16_rtn(__expf(trans[to*KK + frm]));
            }
            #pragma unroll
            for (int q = 0; q < 4; ++q)
                A[tt][kt].u[q] = (unsigned)h[2*q] | ((unsigned)h[2*q+1] << 16);
        }

    f32x4 D[8];
    #pragma unroll
    for (int tt = 0; tt < 8; ++tt) D[tt] = f32x4{0.f,0.f,0.f,0.f};
    if (kg == 3) D[7].w = 1.0f;       // START = tag 127 (tt=7, rr=15)

    // prologue: capture C_0, free slot 0, prefetch flag for slot 1
    while (*(volatile int*)&ready[0] < 2) {}
    f32x4 CA[8], CB[8];
    #pragma unroll
    for (int tt = 0; tt < 8; ++tt)
        CA[tt] = *(const f32x4*)&ring[0][tt*256 + kg*64 + col*4];
    LGKM0();
    if (lane == 0) *(volatile int*)&consr = 1;
    int rdy_pre = *(volatile int*)&ready[1];

    int eap_use = 0, pend = 0, esum = 0;

    auto step = [&](f32x4 (&Cc)[8], f32x4 (&Cn)[8], int t) {
        // ---- B = bf16(D * 2^-eap)  (exact pow2; same-lane identity pack)
        const float sc = __int_as_float((unsigned)(127 - eap_use) << 23);
        AB B[4];
        #pragma unroll
        for (int kt = 0; kt < 4; ++kt) {
            f32x4 da = D[2*kt]   * sc;
            f32x4 db = D[2*kt+1] * sc;
            B[kt].u[0] = cvt_pk_bf16(da.x, da.y);
            B[kt].u[1] = cvt_pk_bf16(da.z, da.w);
            B[kt].u[2] = cvt_pk_bf16(db.x, db.y);
            B[kt].u[3] = cvt_pk_bf16(db.z, db.w);
        }
        esum += eap_use;

        // ---- M = E . B, kt-major (independent consecutive MFMAs)
        f32x4 M[8];
        #pragma unroll
        for (int tt = 0; tt < 8; ++tt) M[tt] = f32x4{0.f,0.f,0.f,0.f};
        #pragma unroll
        for (int kt = 0; kt < 4; ++kt)
            #pragma unroll
            for (int tt = 0; tt < 8; ++tt)
                M[tt] = __builtin_amdgcn_mfma_f32_16x16x32_bf16(A[tt][kt].v, B[kt].v, M[tt], 0, 0, 0);

        // ---- capture C_{t+1} under the MFMA train; free its slot
        if (t + 1 < TT) {
            const int s1  = (t + 1) & (NS - 1);
            const int tg1 = 2 * (((t + 1) >> 3) + 1);
            if (rdy_pre < tg1)
                while (*(volatile int*)&ready[s1] < tg1) {}
            #pragma unroll
            for (int tt = 0; tt < 8; ++tt)
                Cn[tt] = *(const f32x4*)&ring[s1][tt*256 + kg*64 + col*4];
            LGKM0();                      // reads landed ("memory" pins order)
            if (lane == 0) *(volatile int*)&consr = t + 2;
            rdy_pre = *(volatile int*)&ready[(t + 2) & (NS - 1)];
        }

        // ---- D' = min(M*C, 1e30); tt=0 first so bpermute launches early
        {
            f32x4 p0 = M[0] * Cc[0];
            D[0].x = fminf(p0.x, 1e30f); D[0].y = fminf(p0.y, 1e30f);
            D[0].z = fminf(p0.z, 1e30f); D[0].w = fminf(p0.w, 1e30f);
        }
        eap_use = pend < -16 ? -16 : (pend > 48 ? 48 : pend);  // stale-2, exact via esum
        const int ex = (int)((__float_as_uint(D[0].x) >> 23) & 255u) - 127;
        pend = __builtin_amdgcn_ds_bpermute(col << 2, ex);
        #pragma unroll
        for (int tt = 1; tt < 8; ++tt) {
            f32x4 p = M[tt] * Cc[tt];
            D[tt].x = fminf(p.x, 1e30f); D[tt].y = fminf(p.y, 1e30f);
            D[tt].z = fminf(p.z, 1e30f); D[tt].w = fminf(p.w, 1e30f);
        }
    };

    for (int t = 0; t < TT; t += 2) {
        step(CA, CB, t);
        step(CB, CA, t + 1);
    }

    // ---- out[seq] = ln2*esum + log( sum_tag D_T[tag] * exp(trans[END][tag]) )
    float S = 0.f;
    #pragma unroll
    for (int tt = 0; tt < 8; ++tt) {
        const float* pe = trans + (size_t)(KK - 2) * KK + tt*16 + kg*4;
        S += D[tt].x * __expf(pe[0]);
        S += D[tt].y * __expf(pe[1]);
        S += D[tt].z * __expf(pe[2]);
        S += D[tt].w * __expf(pe[3]);
    }
    S += __shfl_xor(S, 16, 64);
    S += __shfl_xor(S, 32, 64);
    if (lane < 16) out[seq] = LN2F * (float)esum + __logf(S);
}

extern "C" void kernel_launch(void* const* d_in, const int* in_sizes, int n_in,
                              void* d_out, int out_size, void* d_ws, size_t ws_size,
                              hipStream_t stream) {
    const float* feats = (const float*)d_in[0];  // [B, T, K] f32
    const float* trans = (const float*)d_in[1];  // [K, K] f32
    float* out = (float*)d_out;                  // [B] f32

    crf_fwd_kernel<<<NBLK, TPB, 0, stream>>>(feats, trans, out);
}